// Round 13
// baseline (288.974 us; speedup 1.0000x reference)
//
#include <hip/hip_runtime.h>
#include <hip/hip_bf16.h>
#include <math.h>

// Problem sizes (fixed)
#define NROW    4096
#define DPROJ   1024
#define LDHB    1408         // Hb row stride (bf16 elems)
#define LDA8    1536         // A8 row stride (bytes): 1024 head | 256 t1 | 128 t2 | 128 t3
#define HEAD_V  20003
#define TAIL_V  10000
#define HEAD_VP 20224        // 158*128
#define TAIL1_P 10240        // 80*128
#define TAIL_VP 10112        // 79*128
#define NBH     158
#define NBT1    80
#define NBT     79
#define L2E     1.44269504088896f

// cast_all block ranges
#define CB_H    4096                 // hidden cast
#define CB_P    (CB_H + 352)         // transpose proj
#define CB_W0   (CB_P + 20224)       // head w fp8
#define CB_W1   (CB_W0 + 2560)       // tail1 w fp8 (4 rows/block)
#define CB_W2   (CB_W1 + 1264)       // tail2 w fp8 (8 rows/block)
#define CB_W3   (CB_W2 + 1264)       // tail3 w fp8 (8 rows/block)
#define CB_BH   (CB_W3 + 20)         // bpH (20224 floats)
#define CB_B1   (CB_BH + 10)         // bp1 (10240)
#define CB_B2   (CB_B1 + 10)         // bp2 (10112)
#define CB_B3   (CB_B2 + 10)         // bp3 (10112)

typedef short short8 __attribute__((ext_vector_type(8)));
typedef float f32x4  __attribute__((ext_vector_type(4)));
typedef long  i64x2  __attribute__((ext_vector_type(2)));
typedef int   i32x8  __attribute__((ext_vector_type(8)));

__device__ __forceinline__ ushort f2bf(float f) {           // RNE f32 -> bf16
    unsigned u = __builtin_bit_cast(unsigned, f);
    return (ushort)((u + 0x7FFFu + ((u >> 16) & 1u)) >> 16);
}
__device__ __forceinline__ float bf2f(ushort u) {
    unsigned x = (unsigned)u << 16;
    return __builtin_bit_cast(float, x);
}
// within-128 K permutation (involution on byte addr bits)
__device__ __forceinline__ int kperm(int q) {
    int q7 = q & 127;
    return (q & ~127) + ((q7 >> 3) & 3) * 32 + ((q7 >> 5) << 3) + (q7 & 7);
}

#define GLOAD16(gp, lp) __builtin_amdgcn_global_load_lds(                     \
    (const __attribute__((address_space(1))) void*)(gp),                      \
    (__attribute__((address_space(3))) void*)(lp), 16, 0, 0)

// ---------------------------------------------------------------------------
// cast_all: one launch, range-dispatched on blockIdx.x
// ---------------------------------------------------------------------------
__global__ void cast_all(const float* __restrict__ hidden,
                         const float* __restrict__ p0, const float* __restrict__ p1,
                         const float* __restrict__ p2, const float* __restrict__ p3,
                         const float* __restrict__ w0, const float* __restrict__ cw,
                         const float* __restrict__ w1, const float* __restrict__ w2,
                         const float* __restrict__ w3,
                         const float* __restrict__ b0, const float* __restrict__ cbv,
                         const float* __restrict__ b1, const float* __restrict__ b2,
                         const float* __restrict__ b3,
                         ushort* __restrict__ hb, ushort* __restrict__ pbT,
                         unsigned char* __restrict__ WH8, unsigned char* __restrict__ WT18,
                         unsigned char* __restrict__ WT28, unsigned char* __restrict__ WT38,
                         float* __restrict__ bpH, float* __restrict__ bp1,
                         float* __restrict__ bp2, float* __restrict__ bp3) {
    const int b = blockIdx.x;
    const int t = threadIdx.x;
    if (b < CB_H) {
        int i = (b * 256 + t) * 4;
        float4 v = *(const float4*)(hidden + i);
        ushort4 o = {f2bf(v.x), f2bf(v.y), f2bf(v.z), f2bf(v.w)};
        *(ushort4*)(hb + i) = o;
    } else if (b < CB_P) {
        __shared__ float tile[64][65];
        int r  = b - CB_H;
        int kb = (r & 15) * 64;
        int cb = (r >> 4) * 64;
        for (int p = 0; p < 4; ++p) {
            int kl = p * 16 + (t >> 4);
            int c4 = (t & 15) * 4;
            int k  = kb + kl;
            for (int j = 0; j < 4; ++j) {
                int c = cb + c4 + j;
                float v = 0.f;
                if      (c < 1024) v = p0[(size_t)k * 1024 + c];
                else if (c < 1280) v = p1[(size_t)k * 256  + (c - 1024)];
                else if (c < 1344) v = p2[(size_t)k * 64   + (c - 1280)];
                else if (c < 1360) v = p3[(size_t)k * 16   + (c - 1344)];
                tile[kl][c4 + j] = v;
            }
        }
        __syncthreads();
        for (int p = 0; p < 4; ++p) {
            int cl = p * 16 + (t >> 4);
            int k4 = (t & 15) * 4;
            ushort4 o = {f2bf(tile[k4 + 0][cl]), f2bf(tile[k4 + 1][cl]),
                         f2bf(tile[k4 + 2][cl]), f2bf(tile[k4 + 3][cl])};
            *(ushort4*)(pbT + (size_t)(cb + cl) * 1024 + kb + k4) = o;
        }
    } else if (b < CB_W0) {
        int row = b - CB_P;
        int q   = t * 4;
        int k   = kperm(q);
        float4 v = {0.f, 0.f, 0.f, 0.f};
        if (row < 20000)      v = *(const float4*)(w0 + (size_t)row * 1024 + k);
        else if (row < 20003) v = *(const float4*)(cw + (size_t)(row - 20000) * 1024 + k);
        int p = __builtin_amdgcn_cvt_pk_fp8_f32(v.x, v.y, 0, false);
        p     = __builtin_amdgcn_cvt_pk_fp8_f32(v.z, v.w, p, true);
        *(int*)(WH8 + (size_t)row * 1024 + q) = p;
    } else if (b < CB_W1) {
        int row  = (b - CB_W0) * 4 + (t >> 6);
        int q    = (t & 63) * 4;
        int k    = kperm(q);
        float4 v = {0.f, 0.f, 0.f, 0.f};
        if (row < 10000) v = *(const float4*)(w1 + (size_t)row * 256 + k);
        int p = __builtin_amdgcn_cvt_pk_fp8_f32(v.x, v.y, 0, false);
        p     = __builtin_amdgcn_cvt_pk_fp8_f32(v.z, v.w, p, true);
        *(int*)(WT18 + (size_t)row * 256 + q) = p;
    } else if (b < CB_W2) {
        int row = (b - CB_W1) * 8 + (t >> 5);
        int q   = (t & 31) * 4;
        int k   = kperm(q);
        float4 v = {0.f, 0.f, 0.f, 0.f};
        if (row < 10000 && k < 64) v = *(const float4*)(w2 + (size_t)row * 64 + k);
        int p = __builtin_amdgcn_cvt_pk_fp8_f32(v.x, v.y, 0, false);
        p     = __builtin_amdgcn_cvt_pk_fp8_f32(v.z, v.w, p, true);
        *(int*)(WT28 + (size_t)row * 128 + q) = p;
    } else if (b < CB_W3) {
        int row = (b - CB_W2) * 8 + (t >> 5);
        int q   = (t & 31) * 4;
        int k   = kperm(q);
        float4 v = {0.f, 0.f, 0.f, 0.f};
        if (row < 10000 && k < 16) v = *(const float4*)(w3 + (size_t)row * 16 + k);
        int p = __builtin_amdgcn_cvt_pk_fp8_f32(v.x, v.y, 0, false);
        p     = __builtin_amdgcn_cvt_pk_fp8_f32(v.z, v.w, p, true);
        *(int*)(WT38 + (size_t)row * 128 + q) = p;
    } else if (b < CB_BH) {
        int i0 = (b - CB_W3) * 1024 + t * 4;
        for (int j = 0; j < 4; ++j) {
            int i = i0 + j;
            if (i < HEAD_VP) {
                float v;
                if (i < 20000)      v = b0[i] * L2E;
                else if (i < 20003) v = cbv[i - 20000] * L2E;
                else                v = -1e30f;
                bpH[i] = v;
            }
        }
    } else if (b < CB_B1) {
        int i0 = (b - CB_BH) * 1024 + t * 4;
        for (int j = 0; j < 4; ++j) {
            int i = i0 + j;
            if (i < TAIL1_P) bp1[i] = (i < TAIL_V) ? b1[i] * L2E : -1e30f;
        }
    } else if (b < CB_B2) {
        int i0 = (b - CB_B1) * 1024 + t * 4;
        for (int j = 0; j < 4; ++j) {
            int i = i0 + j;
            if (i < TAIL_VP) bp2[i] = (i < TAIL_V) ? b2[i] * L2E : -1e30f;
        }
    } else {
        int i0 = (b - CB_B2) * 1024 + t * 4;
        for (int j = 0; j < 4; ++j) {
            int i = i0 + j;
            if (i < TAIL_VP) bp3[i] = (i < TAIL_V) ? b3[i] * L2E : -1e30f;
        }
    }
}

// ---------------------------------------------------------------------------
// cast_A8: Hb bf16 -> A8 fp8 scaled by log2(e), K-permuted, 1536 B/row
// ---------------------------------------------------------------------------
__global__ void cast_A8(const ushort* __restrict__ Hb, unsigned char* __restrict__ dst) {
    int row = blockIdx.x;
    for (int i = threadIdx.x; i < LDA8 / 4; i += 256) {
        int q = i * 4;
        int k = kperm(q);
        float4 v = {0.f, 0.f, 0.f, 0.f};
        const ushort* s = nullptr;
        if (k < 1344)      s = Hb + (size_t)row * LDHB + k;
        else if (k >= 1408 && k < 1424) s = Hb + (size_t)row * LDHB + 1344 + (k - 1408);
        if (s) { v.x = bf2f(s[0]) * L2E; v.y = bf2f(s[1]) * L2E;
                 v.z = bf2f(s[2]) * L2E; v.w = bf2f(s[3]) * L2E; }
        int p = __builtin_amdgcn_cvt_pk_fp8_f32(v.x, v.y, 0, false);
        p     = __builtin_amdgcn_cvt_pk_fp8_f32(v.z, v.w, p, true);
        *(int*)(dst + (size_t)row * LDA8 + q) = p;
    }
}

// ---------------------------------------------------------------------------
// Proj GEMM: Hb[4096][1408] = hb @ pbT^T  (m97 128x128, bf16)
// ---------------------------------------------------------------------------
__global__ __launch_bounds__(256) void proj_gemm_mfma(const ushort* __restrict__ A,
                                                      const ushort* __restrict__ B,
                                                      ushort* __restrict__ C) {
    __shared__ ushort As[128 * 32];
    __shared__ ushort Bs[128 * 32];
    const int t  = threadIdx.x;
    const int wv = t >> 6, l = t & 63, lr = l & 15, lh = l >> 4;
    const int wr = wv >> 1, wc = wv & 1;
    const int rb = blockIdx.x * 128, cb = blockIdx.y * 128;
    f32x4 acc[4][4] = {};
    for (int k0 = 0; k0 < DPROJ; k0 += 32) {
        __syncthreads();
        #pragma unroll
        for (int is = 0; is < 2; ++is) {
            int rr = (t >> 2) + is * 64;
            GLOAD16(A + (size_t)(rb + rr) * DPROJ + k0 + (t & 3) * 8,
                    (char*)As + wv * 1024 + is * 4096);
            GLOAD16(B + (size_t)(cb + rr) * DPROJ + k0 + (t & 3) * 8,
                    (char*)Bs + wv * 1024 + is * 4096);
        }
        __syncthreads();
        short8 af[4], bf[4];
        #pragma unroll
        for (int m = 0; m < 4; ++m)
            af[m] = *(const short8*)(As + (wr * 64 + m * 16 + lr) * 32 + lh * 8);
        #pragma unroll
        for (int n = 0; n < 4; ++n)
            bf[n] = *(const short8*)(Bs + (wc * 64 + n * 16 + lr) * 32 + lh * 8);
        #pragma unroll
        for (int m = 0; m < 4; ++m)
            #pragma unroll
            for (int n = 0; n < 4; ++n)
                acc[m][n] = __builtin_amdgcn_mfma_f32_16x16x32_bf16(af[m], bf[n], acc[m][n], 0, 0, 0);
    }
    #pragma unroll
    for (int m = 0; m < 4; ++m)
        #pragma unroll
        for (int n = 0; n < 4; ++n)
            #pragma unroll
            for (int r = 0; r < 4; ++r) {
                int rl = wr * 64 + m * 16 + lh * 4 + r;
                int cl = wc * 64 + n * 16 + lr;
                C[(size_t)(rb + rl) * LDHB + cb + cl] = f2bf(acc[m][n][r]);
            }
}

// ---------------------------------------------------------------------------
// Unified FP8 128x128 GEMM + sum-exp (log2 domain), MX-scaled MFMA K=128,
// scale=1.0 (e8m0 0x7F). SPILL FIX vs R12: m-loop split into two halves so
// only 2 A-tuples (16 regs) + 1 B-tuple (8) are live per MFMA cluster
// (R12 held 4+1 aligned i32x8 tuples -> allocator spilled 71 MB of scratch).
// B fragments re-read per half (LDS aggregate ~31 us < 51 us MFMA floor).
// BK=128 B, 4 waves, 32 KB LDS, 4 blocks/CU (128 reg/wave budget).
// ---------------------------------------------------------------------------
__global__ __launch_bounds__(256, 4) void gemm_sumexp_all(
        const unsigned char* __restrict__ A8,
        const unsigned char* __restrict__ WH8, const unsigned char* __restrict__ WT18,
        const unsigned char* __restrict__ WT28, const unsigned char* __restrict__ WT38,
        const float* __restrict__ bpH, const float* __restrict__ bp1,
        const float* __restrict__ bp2, const float* __restrict__ bp3,
        float* __restrict__ pH, float* __restrict__ pT1,
        float* __restrict__ pT2, float* __restrict__ pT3) {
    const int y = blockIdx.y;
    const unsigned char* B;
    const float* bias;
    float* partial;
    int aoff, K, nCB, cbY;
    if (y < NBH) {
        B = WH8;  bias = bpH; partial = pH;
        aoff = 0;    K = 1024; nCB = NBH;  cbY = y;
    } else if (y < NBH + NBT1) {
        B = WT18; bias = bp1; partial = pT1;
        aoff = 1024; K = 256;  nCB = NBT1; cbY = y - NBH;
    } else if (y < NBH + NBT1 + NBT) {
        B = WT28; bias = bp2; partial = pT2;
        aoff = 1280; K = 128;  nCB = NBT;  cbY = y - NBH - NBT1;
    } else {
        B = WT38; bias = bp3; partial = pT3;
        aoff = 1408; K = 128;  nCB = NBT;  cbY = y - NBH - NBT1 - NBT;
    }

    __shared__ char As[128 * 128];
    __shared__ char Bs[128 * 128];
    const int t  = threadIdx.x;
    const int wv = t >> 6, l = t & 63, lr = l & 15, lh = l >> 4;
    const int wr = wv >> 1, wc = wv & 1;
    const int rb = blockIdx.x * 128, cb = cbY * 128;
    const int jr  = t >> 3;
    const int csw = (((l & 7) ^ (l >> 3)) << 4);

    const unsigned char* Ab = A8 + aoff;
    f32x4 acc[4][4] = {};
    const int kNT = K >> 7;
    for (int kt = 0; kt < kNT; ++kt) {
        const int k0 = kt * 128;
        __syncthreads();
        #pragma unroll
        for (int j = 0; j < 4; ++j) {
            int rr = j * 32 + jr;
            GLOAD16(Ab + (size_t)(rb + rr) * LDA8 + k0 + csw, As + j * 4096 + wv * 1024);
            GLOAD16(B  + (size_t)(cb + rr) * K    + k0 + csw, Bs + j * 4096 + wv * 1024);
        }
        __syncthreads();
        #pragma unroll
        for (int mh = 0; mh < 2; ++mh) {
            i32x8 av[2];
            #pragma unroll
            for (int mm = 0; mm < 2; ++mm) {
                int row = wr * 64 + (mh * 2 + mm) * 16 + lr;
                i64x2* h = (i64x2*)&av[mm];
                #pragma unroll
                for (int s = 0; s < 2; ++s)
                    h[s] = *(const i64x2*)(As + row * 128 + ((lh * 32 + s * 16) ^ ((row & 7) << 4)));
            }
            #pragma unroll
            for (int n = 0; n < 4; ++n) {
                i32x8 bv;
                int row = wc * 64 + n * 16 + lr;
                i64x2* h = (i64x2*)&bv;
                #pragma unroll
                for (int s = 0; s < 2; ++s)
                    h[s] = *(const i64x2*)(Bs + row * 128 + ((lh * 32 + s * 16) ^ ((row & 7) << 4)));
                #pragma unroll
                for (int mm = 0; mm < 2; ++mm)
                    acc[mh * 2 + mm][n] = __builtin_amdgcn_mfma_scale_f32_16x16x128_f8f6f4(
                        av[mm], bv, acc[mh * 2 + mm][n], 0, 0,
                        0, 0x7F7F7F7F, 0, 0x7F7F7F7F);
            }
        }
    }
    // epilogue: s += exp2(acc + bias_l2e); padded cols contribute exactly 0
    float bvx[4];
    #pragma unroll
    for (int n = 0; n < 4; ++n) bvx[n] = bias[cb + wc * 64 + n * 16 + lr];
    float rs[4][4];
    #pragma unroll
    for (int m = 0; m < 4; ++m)
        #pragma unroll
        for (int r = 0; r < 4; ++r) {
            float s = 0.f;
            #pragma unroll
            for (int n = 0; n < 4; ++n)
                s += __builtin_amdgcn_exp2f(acc[m][n][r] + bvx[n]);
            rs[m][r] = s;
        }
    __syncthreads();                       // all reads of As done -> reuse as red
    float* red = (float*)As;               // [2][128]
    #pragma unroll
    for (int m = 0; m < 4; ++m)
        #pragma unroll
        for (int r = 0; r < 4; ++r) {
            #pragma unroll
            for (int off = 1; off < 16; off <<= 1)
                rs[m][r] += __shfl_xor(rs[m][r], off);
            if (lr == 0) red[wc * 128 + wr * 64 + m * 16 + lh * 4 + r] = rs[m][r];
        }
    __syncthreads();
    if (t < 128)
        partial[(size_t)(rb + t) * nCB + cbY] = red[t] + red[128 + t];
}

// ---------------------------------------------------------------------------
// Finalize: one wave per row — gather target/cluster logits (fp32), assemble NLL.
// ---------------------------------------------------------------------------
__global__ void pals_finalize(const ushort* __restrict__ Hb,
                              const int* __restrict__ target,
                              const float* __restrict__ w0, const float* __restrict__ b0,
                              const float* __restrict__ w1, const float* __restrict__ b1,
                              const float* __restrict__ w2, const float* __restrict__ b2,
                              const float* __restrict__ w3, const float* __restrict__ b3,
                              const float* __restrict__ cw, const float* __restrict__ cbv,
                              const float* __restrict__ pH,
                              const float* __restrict__ pT1,
                              const float* __restrict__ pT2,
                              const float* __restrict__ pT3,
                              float* __restrict__ out) {
    const int wave = threadIdx.x >> 6;
    const int lane = threadIdx.x & 63;
    const int row  = blockIdx.x * 4 + wave;
    if (row >= NROW) return;
    const int t = target[row];
    const ushort* Hrow = Hb + (size_t)row * LDHB;

    float s = 0.f;
    for (int c = lane; c < NBH; c += 64) s += pH[(size_t)row * NBH + c];
    #pragma unroll
    for (int off = 32; off; off >>= 1) s += __shfl_xor(s, off);
    const float logSh = logf(s);

    float nll;
    if (t < 20000) {
        const float* wr0 = w0 + (size_t)t * 1024;
        float d = 0.f;
        for (int k = lane * 4; k < 1024; k += 256) {
            ushort4 a = *(const ushort4*)(Hrow + k);
            float4  b = *(const float4*)(wr0 + k);
            d += bf2f(a.x) * b.x + bf2f(a.y) * b.y + bf2f(a.z) * b.z + bf2f(a.w) * b.w;
        }
        #pragma unroll
        for (int off = 32; off; off >>= 1) d += __shfl_xor(d, off);
        nll = -(d + b0[t] - logSh);
    } else {
        const int i  = (t - 20000) / 10000 + 1;        // 1..3
        const int ci = 3 - i;                           // head_lp[:, -i] quirk
        const float* cwr = cw + (size_t)ci * 1024;
        float d = 0.f;
        for (int k = lane * 4; k < 1024; k += 256) {
            ushort4 a = *(const ushort4*)(Hrow + k);
            float4  b = *(const float4*)(cwr + k);
            d += bf2f(a.x) * b.x + bf2f(a.y) * b.y + bf2f(a.z) * b.z + bf2f(a.w) * b.w;
        }
        #pragma unroll
        for (int off = 32; off; off >>= 1) d += __shfl_xor(d, off);
        const float logit_c = d + cbv[ci];

        const int dl   = 1024 >> (2 * i);               // 256, 64, 16
        const int hoff = (i == 1) ? 1024 : (i == 2) ? 1280 : 1344;
        const float* wi = (i == 1) ? w1 : (i == 2) ? w2 : w3;
        const float* bi = (i == 1) ? b1 : (i == 2) ? b2 : b3;
        const float* pT = (i == 1) ? pT1 : (i == 2) ? pT2 : pT3;
        const int nbi  = (i == 1) ? NBT1 : NBT;
        const int tt = t - (20000 + (i - 1) * 10000);

        float dt = 0.f;
        const ushort* Hi = Hrow + hoff;
        for (int k = lane; k < dl; k += 64) dt += bf2f(Hi[k]) * wi[(size_t)tt * dl + k];
        #pragma unroll
        for (int off = 32; off; off >>= 1) dt += __shfl_xor(dt, off);

        float st = 0.f;
        for (int c = lane; c < nbi; c += 64) st += pT[(size_t)row * nbi + c];
        #pragma unroll
        for (int off = 32; off; off >>= 1) st += __shfl_xor(st, off);

        nll = -((logit_c - logSh) + (dt + bi[tt] - logf(st)));
    }
    if (lane == 0) out[row] = nll;
}

// ---------------------------------------------------------------------------
extern "C" void kernel_launch(void* const* d_in, const int* in_sizes, int n_in,
                              void* d_out, int out_size, void* d_ws, size_t ws_size,
                              hipStream_t stream) {
    const float* hidden = (const float*)d_in[0];
    const int*   target = (const int*)  d_in[1];
    const float* proj0  = (const float*)d_in[2];
    const float* w0     = (const float*)d_in[3];
    const float* b0     = (const float*)d_in[4];
    const float* proj1  = (const float*)d_in[5];
    const float* w1     = (const float*)d_in[6];
    const float* b1     = (const float*)d_in[7];
    const float* proj2  = (const float*)d_in[8];
    const float* w2     = (const float*)d_in[9];
    const float* b2     = (const float*)d_in[10];
    const float* proj3  = (const float*)d_in[11];
    const float* w3     = (const float*)d_in[12];
    const float* b3     = (const float*)d_in[13];
    const float* cw     = (const float*)d_in[14];
    const float* cbv    = (const float*)d_in[15];

    ushort* hb  = (ushort*)d_ws;                         // [4096][1024]
    ushort* pbT = hb  + (size_t)NROW * DPROJ;            // [1408][1024]
    ushort* Hb  = pbT + (size_t)LDHB * DPROJ;            // [4096][1408]
    unsigned char* WH8  = (unsigned char*)(Hb + (size_t)NROW * LDHB);    // [20224][1024]
    unsigned char* WT18 = WH8  + (size_t)HEAD_VP * 1024;                 // [10240][256]
    unsigned char* WT28 = WT18 + (size_t)TAIL1_P * 256;                  // [10112][128]
    unsigned char* WT38 = WT28 + (size_t)TAIL_VP * 128;                  // [10112][128]
    unsigned char* A8   = WT38 + (size_t)TAIL_VP * 128;                  // [4096][1536]
    float*  bpH = (float*)(A8 + (size_t)NROW * LDA8);    // [20224]
    float*  bp1 = bpH + HEAD_VP;                         // [10240]
    float*  bp2 = bp1 + TAIL1_P;                         // [10112]
    float*  bp3 = bp2 + TAIL_VP;                         // [10112]
    float*  pH  = bp3 + TAIL_VP;                         // [4096][158]
    float*  pT1 = pH  + (size_t)NROW * NBH;              // [4096][80]
    float*  pT2 = pT1 + (size_t)NROW * NBT1;             // [4096][79]
    float*  pT3 = pT2 + (size_t)NROW * NBT;              // [4096][79]

    dim3 blk(256);
    cast_all<<<dim3(CB_B3), blk, 0, stream>>>(
        hidden, proj0, proj1, proj2, proj3, w0, cw, w1, w2, w3,
        b0, cbv, b1, b2, b3,
        hb, pbT, WH8, WT18, WT28, WT38, bpH, bp1, bp2, bp3);

    proj_gemm_mfma<<<dim3(32, 11), blk, 0, stream>>>(hb, pbT, Hb);
    cast_A8<<<dim3(NROW), blk, 0, stream>>>(Hb, A8);

    // all 4 logits GEMMs in one launch: 32 x 396 grid, 4 blocks/CU
    gemm_sumexp_all<<<dim3(32, NBH + NBT1 + NBT + NBT), blk, 0, stream>>>(
        A8, WH8, WT18, WT28, WT38, bpH, bp1, bp2, bp3, pH, pT1, pT2, pT3);

    pals_finalize<<<dim3(NROW / 4), blk, 0, stream>>>(
        Hb, target, w0, b0, w1, b1, w2, b2, w3, b3, cw, cbv,
        pH, pT1, pT2, pT3, (float*)d_out);
}

// Round 14
// 216.948 us; speedup vs baseline: 1.3320x; 1.3320x over previous
//
#include <hip/hip_runtime.h>
#include <hip/hip_bf16.h>
#include <math.h>

// Problem sizes (fixed)
#define NROW    4096
#define DPROJ   1024
#define LDHB    1408         // Hb row stride (bf16 elems)
#define LDA8    1536         // A8 row stride (bytes): 1024 head | 256 t1 | 128 t2 | 128 t3
#define HEAD_V  20003
#define TAIL_V  10000
#define HEAD_VP 20224        // 158*128
#define TAIL1_P 10240        // 80*128
#define TAIL_VP 10112        // 79*128
#define NBH     158
#define NBT1    80
#define NBT     79
#define L2E     1.44269504088896f

// cast_all block ranges
#define CB_H    4096                 // hidden cast
#define CB_P    (CB_H + 352)         // transpose proj
#define CB_W0   (CB_P + 20224)       // head w fp8
#define CB_W1   (CB_W0 + 2560)       // tail1 w fp8 (4 rows/block)
#define CB_W2   (CB_W1 + 1264)       // tail2 w fp8 (8 rows/block)
#define CB_W3   (CB_W2 + 1264)       // tail3 w fp8 (8 rows/block)
#define CB_BH   (CB_W3 + 20)         // bpH (20224 floats)
#define CB_B1   (CB_BH + 10)         // bp1 (10240)
#define CB_B2   (CB_B1 + 10)         // bp2 (10112)
#define CB_B3   (CB_B2 + 10)         // bp3 (10112)

typedef short short8 __attribute__((ext_vector_type(8)));
typedef float f32x4  __attribute__((ext_vector_type(4)));
typedef long  i64x2  __attribute__((ext_vector_type(2)));
typedef int   i32x8  __attribute__((ext_vector_type(8)));

__device__ __forceinline__ ushort f2bf(float f) {           // RNE f32 -> bf16
    unsigned u = __builtin_bit_cast(unsigned, f);
    return (ushort)((u + 0x7FFFu + ((u >> 16) & 1u)) >> 16);
}
__device__ __forceinline__ float bf2f(ushort u) {
    unsigned x = (unsigned)u << 16;
    return __builtin_bit_cast(float, x);
}
// within-128 K permutation (involution on byte addr bits)
__device__ __forceinline__ int kperm(int q) {
    int q7 = q & 127;
    return (q & ~127) + ((q7 >> 3) & 3) * 32 + ((q7 >> 5) << 3) + (q7 & 7);
}

#define GLOAD16(gp, lp) __builtin_amdgcn_global_load_lds(                     \
    (const __attribute__((address_space(1))) void*)(gp),                      \
    (__attribute__((address_space(3))) void*)(lp), 16, 0, 0)

// ---------------------------------------------------------------------------
// cast_all: one launch, range-dispatched on blockIdx.x
// ---------------------------------------------------------------------------
__global__ void cast_all(const float* __restrict__ hidden,
                         const float* __restrict__ p0, const float* __restrict__ p1,
                         const float* __restrict__ p2, const float* __restrict__ p3,
                         const float* __restrict__ w0, const float* __restrict__ cw,
                         const float* __restrict__ w1, const float* __restrict__ w2,
                         const float* __restrict__ w3,
                         const float* __restrict__ b0, const float* __restrict__ cbv,
                         const float* __restrict__ b1, const float* __restrict__ b2,
                         const float* __restrict__ b3,
                         ushort* __restrict__ hb, ushort* __restrict__ pbT,
                         unsigned char* __restrict__ WH8, unsigned char* __restrict__ WT18,
                         unsigned char* __restrict__ WT28, unsigned char* __restrict__ WT38,
                         float* __restrict__ bpH, float* __restrict__ bp1,
                         float* __restrict__ bp2, float* __restrict__ bp3) {
    const int b = blockIdx.x;
    const int t = threadIdx.x;
    if (b < CB_H) {
        int i = (b * 256 + t) * 4;
        float4 v = *(const float4*)(hidden + i);
        ushort4 o = {f2bf(v.x), f2bf(v.y), f2bf(v.z), f2bf(v.w)};
        *(ushort4*)(hb + i) = o;
    } else if (b < CB_P) {
        __shared__ float tile[64][65];
        int r  = b - CB_H;
        int kb = (r & 15) * 64;
        int cb = (r >> 4) * 64;
        for (int p = 0; p < 4; ++p) {
            int kl = p * 16 + (t >> 4);
            int c4 = (t & 15) * 4;
            int k  = kb + kl;
            for (int j = 0; j < 4; ++j) {
                int c = cb + c4 + j;
                float v = 0.f;
                if      (c < 1024) v = p0[(size_t)k * 1024 + c];
                else if (c < 1280) v = p1[(size_t)k * 256  + (c - 1024)];
                else if (c < 1344) v = p2[(size_t)k * 64   + (c - 1280)];
                else if (c < 1360) v = p3[(size_t)k * 16   + (c - 1344)];
                tile[kl][c4 + j] = v;
            }
        }
        __syncthreads();
        for (int p = 0; p < 4; ++p) {
            int cl = p * 16 + (t >> 4);
            int k4 = (t & 15) * 4;
            ushort4 o = {f2bf(tile[k4 + 0][cl]), f2bf(tile[k4 + 1][cl]),
                         f2bf(tile[k4 + 2][cl]), f2bf(tile[k4 + 3][cl])};
            *(ushort4*)(pbT + (size_t)(cb + cl) * 1024 + kb + k4) = o;
        }
    } else if (b < CB_W0) {
        int row = b - CB_P;
        int q   = t * 4;
        int k   = kperm(q);
        float4 v = {0.f, 0.f, 0.f, 0.f};
        if (row < 20000)      v = *(const float4*)(w0 + (size_t)row * 1024 + k);
        else if (row < 20003) v = *(const float4*)(cw + (size_t)(row - 20000) * 1024 + k);
        int p = __builtin_amdgcn_cvt_pk_fp8_f32(v.x, v.y, 0, false);
        p     = __builtin_amdgcn_cvt_pk_fp8_f32(v.z, v.w, p, true);
        *(int*)(WH8 + (size_t)row * 1024 + q) = p;
    } else if (b < CB_W1) {
        int row  = (b - CB_W0) * 4 + (t >> 6);
        int q    = (t & 63) * 4;
        int k    = kperm(q);
        float4 v = {0.f, 0.f, 0.f, 0.f};
        if (row < 10000) v = *(const float4*)(w1 + (size_t)row * 256 + k);
        int p = __builtin_amdgcn_cvt_pk_fp8_f32(v.x, v.y, 0, false);
        p     = __builtin_amdgcn_cvt_pk_fp8_f32(v.z, v.w, p, true);
        *(int*)(WT18 + (size_t)row * 256 + q) = p;
    } else if (b < CB_W2) {
        int row = (b - CB_W1) * 8 + (t >> 5);
        int q   = (t & 31) * 4;
        int k   = kperm(q);
        float4 v = {0.f, 0.f, 0.f, 0.f};
        if (row < 10000 && k < 64) v = *(const float4*)(w2 + (size_t)row * 64 + k);
        int p = __builtin_amdgcn_cvt_pk_fp8_f32(v.x, v.y, 0, false);
        p     = __builtin_amdgcn_cvt_pk_fp8_f32(v.z, v.w, p, true);
        *(int*)(WT28 + (size_t)row * 128 + q) = p;
    } else if (b < CB_W3) {
        int row = (b - CB_W2) * 8 + (t >> 5);
        int q   = (t & 31) * 4;
        int k   = kperm(q);
        float4 v = {0.f, 0.f, 0.f, 0.f};
        if (row < 10000 && k < 16) v = *(const float4*)(w3 + (size_t)row * 16 + k);
        int p = __builtin_amdgcn_cvt_pk_fp8_f32(v.x, v.y, 0, false);
        p     = __builtin_amdgcn_cvt_pk_fp8_f32(v.z, v.w, p, true);
        *(int*)(WT38 + (size_t)row * 128 + q) = p;
    } else if (b < CB_BH) {
        int i0 = (b - CB_W3) * 1024 + t * 4;
        for (int j = 0; j < 4; ++j) {
            int i = i0 + j;
            if (i < HEAD_VP) {
                float v;
                if (i < 20000)      v = b0[i] * L2E;
                else if (i < 20003) v = cbv[i - 20000] * L2E;
                else                v = -1e30f;
                bpH[i] = v;
            }
        }
    } else if (b < CB_B1) {
        int i0 = (b - CB_BH) * 1024 + t * 4;
        for (int j = 0; j < 4; ++j) {
            int i = i0 + j;
            if (i < TAIL1_P) bp1[i] = (i < TAIL_V) ? b1[i] * L2E : -1e30f;
        }
    } else if (b < CB_B2) {
        int i0 = (b - CB_B1) * 1024 + t * 4;
        for (int j = 0; j < 4; ++j) {
            int i = i0 + j;
            if (i < TAIL_VP) bp2[i] = (i < TAIL_V) ? b2[i] * L2E : -1e30f;
        }
    } else {
        int i0 = (b - CB_B2) * 1024 + t * 4;
        for (int j = 0; j < 4; ++j) {
            int i = i0 + j;
            if (i < TAIL_VP) bp3[i] = (i < TAIL_V) ? b3[i] * L2E : -1e30f;
        }
    }
}

// ---------------------------------------------------------------------------
// cast_A8: Hb bf16 -> A8 fp8 scaled by log2(e), K-permuted, 1536 B/row
// ---------------------------------------------------------------------------
__global__ void cast_A8(const ushort* __restrict__ Hb, unsigned char* __restrict__ dst) {
    int row = blockIdx.x;
    for (int i = threadIdx.x; i < LDA8 / 4; i += 256) {
        int q = i * 4;
        int k = kperm(q);
        float4 v = {0.f, 0.f, 0.f, 0.f};
        const ushort* s = nullptr;
        if (k < 1344)      s = Hb + (size_t)row * LDHB + k;
        else if (k >= 1408 && k < 1424) s = Hb + (size_t)row * LDHB + 1344 + (k - 1408);
        if (s) { v.x = bf2f(s[0]) * L2E; v.y = bf2f(s[1]) * L2E;
                 v.z = bf2f(s[2]) * L2E; v.w = bf2f(s[3]) * L2E; }
        int p = __builtin_amdgcn_cvt_pk_fp8_f32(v.x, v.y, 0, false);
        p     = __builtin_amdgcn_cvt_pk_fp8_f32(v.z, v.w, p, true);
        *(int*)(dst + (size_t)row * LDA8 + q) = p;
    }
}

// ---------------------------------------------------------------------------
// Proj GEMM: Hb[4096][1408] = hb @ pbT^T  (m97 128x128, bf16)
// ---------------------------------------------------------------------------
__global__ __launch_bounds__(256) void proj_gemm_mfma(const ushort* __restrict__ A,
                                                      const ushort* __restrict__ B,
                                                      ushort* __restrict__ C) {
    __shared__ ushort As[128 * 32];
    __shared__ ushort Bs[128 * 32];
    const int t  = threadIdx.x;
    const int wv = t >> 6, l = t & 63, lr = l & 15, lh = l >> 4;
    const int wr = wv >> 1, wc = wv & 1;
    const int rb = blockIdx.x * 128, cb = blockIdx.y * 128;
    f32x4 acc[4][4] = {};
    for (int k0 = 0; k0 < DPROJ; k0 += 32) {
        __syncthreads();
        #pragma unroll
        for (int is = 0; is < 2; ++is) {
            int rr = (t >> 2) + is * 64;
            GLOAD16(A + (size_t)(rb + rr) * DPROJ + k0 + (t & 3) * 8,
                    (char*)As + wv * 1024 + is * 4096);
            GLOAD16(B + (size_t)(cb + rr) * DPROJ + k0 + (t & 3) * 8,
                    (char*)Bs + wv * 1024 + is * 4096);
        }
        __syncthreads();
        short8 af[4], bf[4];
        #pragma unroll
        for (int m = 0; m < 4; ++m)
            af[m] = *(const short8*)(As + (wr * 64 + m * 16 + lr) * 32 + lh * 8);
        #pragma unroll
        for (int n = 0; n < 4; ++n)
            bf[n] = *(const short8*)(Bs + (wc * 64 + n * 16 + lr) * 32 + lh * 8);
        #pragma unroll
        for (int m = 0; m < 4; ++m)
            #pragma unroll
            for (int n = 0; n < 4; ++n)
                acc[m][n] = __builtin_amdgcn_mfma_f32_16x16x32_bf16(af[m], bf[n], acc[m][n], 0, 0, 0);
    }
    #pragma unroll
    for (int m = 0; m < 4; ++m)
        #pragma unroll
        for (int n = 0; n < 4; ++n)
            #pragma unroll
            for (int r = 0; r < 4; ++r) {
                int rl = wr * 64 + m * 16 + lh * 4 + r;
                int cl = wc * 64 + n * 16 + lr;
                C[(size_t)(rb + rl) * LDHB + cb + cl] = f2bf(acc[m][n][r]);
            }
}

// ---------------------------------------------------------------------------
// Unified FP8 128x128 GEMM + sum-exp (log2 domain), MX-scaled MFMA K=128,
// scale=1.0 (e8m0 0x7F). R14: launch_bounds(256,3) -> 170 reg/wave budget.
// R12/R13 failed because (256,4) = 128/wave = 64 arch + 64 acc-AGPR exactly,
// leaving zero headroom for the 8-aligned i32x8 operand tuples -> acc spill
// (78/465 MB scratch WRITE). 3 blocks/CU fits the ~144-reg true demand.
// ---------------------------------------------------------------------------
__global__ __launch_bounds__(256, 3) void gemm_sumexp_all(
        const unsigned char* __restrict__ A8,
        const unsigned char* __restrict__ WH8, const unsigned char* __restrict__ WT18,
        const unsigned char* __restrict__ WT28, const unsigned char* __restrict__ WT38,
        const float* __restrict__ bpH, const float* __restrict__ bp1,
        const float* __restrict__ bp2, const float* __restrict__ bp3,
        float* __restrict__ pH, float* __restrict__ pT1,
        float* __restrict__ pT2, float* __restrict__ pT3) {
    const int y = blockIdx.y;
    const unsigned char* B;
    const float* bias;
    float* partial;
    int aoff, K, nCB, cbY;
    if (y < NBH) {
        B = WH8;  bias = bpH; partial = pH;
        aoff = 0;    K = 1024; nCB = NBH;  cbY = y;
    } else if (y < NBH + NBT1) {
        B = WT18; bias = bp1; partial = pT1;
        aoff = 1024; K = 256;  nCB = NBT1; cbY = y - NBH;
    } else if (y < NBH + NBT1 + NBT) {
        B = WT28; bias = bp2; partial = pT2;
        aoff = 1280; K = 128;  nCB = NBT;  cbY = y - NBH - NBT1;
    } else {
        B = WT38; bias = bp3; partial = pT3;
        aoff = 1408; K = 128;  nCB = NBT;  cbY = y - NBH - NBT1 - NBT;
    }

    __shared__ char As[128 * 128];
    __shared__ char Bs[128 * 128];
    const int t  = threadIdx.x;
    const int wv = t >> 6, l = t & 63, lr = l & 15, lh = l >> 4;
    const int wr = wv >> 1, wc = wv & 1;
    const int rb = blockIdx.x * 128, cb = cbY * 128;
    const int jr  = t >> 3;
    const int csw = (((l & 7) ^ (l >> 3)) << 4);

    const unsigned char* Ab = A8 + aoff;
    f32x4 acc[4][4] = {};
    const int kNT = K >> 7;
    for (int kt = 0; kt < kNT; ++kt) {
        const int k0 = kt * 128;
        __syncthreads();
        #pragma unroll
        for (int j = 0; j < 4; ++j) {
            int rr = j * 32 + jr;
            GLOAD16(Ab + (size_t)(rb + rr) * LDA8 + k0 + csw, As + j * 4096 + wv * 1024);
            GLOAD16(B  + (size_t)(cb + rr) * K    + k0 + csw, Bs + j * 4096 + wv * 1024);
        }
        __syncthreads();
        i32x8 av[4];
        #pragma unroll
        for (int m = 0; m < 4; ++m) {
            int row = wr * 64 + m * 16 + lr;
            i64x2* h = (i64x2*)&av[m];
            #pragma unroll
            for (int s = 0; s < 2; ++s)
                h[s] = *(const i64x2*)(As + row * 128 + ((lh * 32 + s * 16) ^ ((row & 7) << 4)));
        }
        #pragma unroll
        for (int n = 0; n < 4; ++n) {
            i32x8 bv;
            int row = wc * 64 + n * 16 + lr;
            i64x2* h = (i64x2*)&bv;
            #pragma unroll
            for (int s = 0; s < 2; ++s)
                h[s] = *(const i64x2*)(Bs + row * 128 + ((lh * 32 + s * 16) ^ ((row & 7) << 4)));
            #pragma unroll
            for (int m = 0; m < 4; ++m)
                acc[m][n] = __builtin_amdgcn_mfma_scale_f32_16x16x128_f8f6f4(
                    av[m], bv, acc[m][n], 0, 0,
                    0, 0x7F7F7F7F, 0, 0x7F7F7F7F);
        }
    }
    // epilogue: s += exp2(acc + bias_l2e); padded cols contribute exactly 0
    float bvx[4];
    #pragma unroll
    for (int n = 0; n < 4; ++n) bvx[n] = bias[cb + wc * 64 + n * 16 + lr];
    float rs[4][4];
    #pragma unroll
    for (int m = 0; m < 4; ++m)
        #pragma unroll
        for (int r = 0; r < 4; ++r) {
            float s = 0.f;
            #pragma unroll
            for (int n = 0; n < 4; ++n)
                s += __builtin_amdgcn_exp2f(acc[m][n][r] + bvx[n]);
            rs[m][r] = s;
        }
    __syncthreads();                       // all reads of As done -> reuse as red
    float* red = (float*)As;               // [2][128]
    #pragma unroll
    for (int m = 0; m < 4; ++m)
        #pragma unroll
        for (int r = 0; r < 4; ++r) {
            #pragma unroll
            for (int off = 1; off < 16; off <<= 1)
                rs[m][r] += __shfl_xor(rs[m][r], off);
            if (lr == 0) red[wc * 128 + wr * 64 + m * 16 + lh * 4 + r] = rs[m][r];
        }
    __syncthreads();
    if (t < 128)
        partial[(size_t)(rb + t) * nCB + cbY] = red[t] + red[128 + t];
}

// ---------------------------------------------------------------------------
// Finalize: one wave per row — gather target/cluster logits (fp32), assemble NLL.
// ---------------------------------------------------------------------------
__global__ void pals_finalize(const ushort* __restrict__ Hb,
                              const int* __restrict__ target,
                              const float* __restrict__ w0, const float* __restrict__ b0,
                              const float* __restrict__ w1, const float* __restrict__ b1,
                              const float* __restrict__ w2, const float* __restrict__ b2,
                              const float* __restrict__ w3, const float* __restrict__ b3,
                              const float* __restrict__ cw, const float* __restrict__ cbv,
                              const float* __restrict__ pH,
                              const float* __restrict__ pT1,
                              const float* __restrict__ pT2,
                              const float* __restrict__ pT3,
                              float* __restrict__ out) {
    const int wave = threadIdx.x >> 6;
    const int lane = threadIdx.x & 63;
    const int row  = blockIdx.x * 4 + wave;
    if (row >= NROW) return;
    const int t = target[row];
    const ushort* Hrow = Hb + (size_t)row * LDHB;

    float s = 0.f;
    for (int c = lane; c < NBH; c += 64) s += pH[(size_t)row * NBH + c];
    #pragma unroll
    for (int off = 32; off; off >>= 1) s += __shfl_xor(s, off);
    const float logSh = logf(s);

    float nll;
    if (t < 20000) {
        const float* wr0 = w0 + (size_t)t * 1024;
        float d = 0.f;
        for (int k = lane * 4; k < 1024; k += 256) {
            ushort4 a = *(const ushort4*)(Hrow + k);
            float4  b = *(const float4*)(wr0 + k);
            d += bf2f(a.x) * b.x + bf2f(a.y) * b.y + bf2f(a.z) * b.z + bf2f(a.w) * b.w;
        }
        #pragma unroll
        for (int off = 32; off; off >>= 1) d += __shfl_xor(d, off);
        nll = -(d + b0[t] - logSh);
    } else {
        const int i  = (t - 20000) / 10000 + 1;        // 1..3
        const int ci = 3 - i;                           // head_lp[:, -i] quirk
        const float* cwr = cw + (size_t)ci * 1024;
        float d = 0.f;
        for (int k = lane * 4; k < 1024; k += 256) {
            ushort4 a = *(const ushort4*)(Hrow + k);
            float4  b = *(const float4*)(cwr + k);
            d += bf2f(a.x) * b.x + bf2f(a.y) * b.y + bf2f(a.z) * b.z + bf2f(a.w) * b.w;
        }
        #pragma unroll
        for (int off = 32; off; off >>= 1) d += __shfl_xor(d, off);
        const float logit_c = d + cbv[ci];

        const int dl   = 1024 >> (2 * i);               // 256, 64, 16
        const int hoff = (i == 1) ? 1024 : (i == 2) ? 1280 : 1344;
        const float* wi = (i == 1) ? w1 : (i == 2) ? w2 : w3;
        const float* bi = (i == 1) ? b1 : (i == 2) ? b2 : b3;
        const float* pT = (i == 1) ? pT1 : (i == 2) ? pT2 : pT3;
        const int nbi  = (i == 1) ? NBT1 : NBT;
        const int tt = t - (20000 + (i - 1) * 10000);

        float dt = 0.f;
        const ushort* Hi = Hrow + hoff;
        for (int k = lane; k < dl; k += 64) dt += bf2f(Hi[k]) * wi[(size_t)tt * dl + k];
        #pragma unroll
        for (int off = 32; off; off >>= 1) dt += __shfl_xor(dt, off);

        float st = 0.f;
        for (int c = lane; c < nbi; c += 64) st += pT[(size_t)row * nbi + c];
        #pragma unroll
        for (int off = 32; off; off >>= 1) st += __shfl_xor(st, off);

        nll = -((logit_c - logSh) + (dt + bi[tt] - logf(st)));
    }
    if (lane == 0) out[row] = nll;
}

// ---------------------------------------------------------------------------
extern "C" void kernel_launch(void* const* d_in, const int* in_sizes, int n_in,
                              void* d_out, int out_size, void* d_ws, size_t ws_size,
                              hipStream_t stream) {
    const float* hidden = (const float*)d_in[0];
    const int*   target = (const int*)  d_in[1];
    const float* proj0  = (const float*)d_in[2];
    const float* w0     = (const float*)d_in[3];
    const float* b0     = (const float*)d_in[4];
    const float* proj1  = (const float*)d_in[5];
    const float* w1     = (const float*)d_in[6];
    const float* b1     = (const float*)d_in[7];
    const float* proj2  = (const float*)d_in[8];
    const float* w2     = (const float*)d_in[9];
    const float* b2     = (const float*)d_in[10];
    const float* proj3  = (const float*)d_in[11];
    const float* w3     = (const float*)d_in[12];
    const float* b3     = (const float*)d_in[13];
    const float* cw     = (const float*)d_in[14];
    const float* cbv    = (const float*)d_in[15];

    ushort* hb  = (ushort*)d_ws;                         // [4096][1024]
    ushort* pbT = hb  + (size_t)NROW * DPROJ;            // [1408][1024]
    ushort* Hb  = pbT + (size_t)LDHB * DPROJ;            // [4096][1408]
    unsigned char* WH8  = (unsigned char*)(Hb + (size_t)NROW * LDHB);    // [20224][1024]
    unsigned char* WT18 = WH8  + (size_t)HEAD_VP * 1024;                 // [10240][256]
    unsigned char* WT28 = WT18 + (size_t)TAIL1_P * 256;                  // [10112][128]
    unsigned char* WT38 = WT28 + (size_t)TAIL_VP * 128;                  // [10112][128]
    unsigned char* A8   = WT38 + (size_t)TAIL_VP * 128;                  // [4096][1536]
    float*  bpH = (float*)(A8 + (size_t)NROW * LDA8);    // [20224]
    float*  bp1 = bpH + HEAD_VP;                         // [10240]
    float*  bp2 = bp1 + TAIL1_P;                         // [10112]
    float*  bp3 = bp2 + TAIL_VP;                         // [10112]
    float*  pH  = bp3 + TAIL_VP;                         // [4096][158]
    float*  pT1 = pH  + (size_t)NROW * NBH;              // [4096][80]
    float*  pT2 = pT1 + (size_t)NROW * NBT1;             // [4096][79]
    float*  pT3 = pT2 + (size_t)NROW * NBT;              // [4096][79]

    dim3 blk(256);
    cast_all<<<dim3(CB_B3), blk, 0, stream>>>(
        hidden, proj0, proj1, proj2, proj3, w0, cw, w1, w2, w3,
        b0, cbv, b1, b2, b3,
        hb, pbT, WH8, WT18, WT28, WT38, bpH, bp1, bp2, bp3);

    proj_gemm_mfma<<<dim3(32, 11), blk, 0, stream>>>(hb, pbT, Hb);
    cast_A8<<<dim3(NROW), blk, 0, stream>>>(Hb, A8);

    // all 4 logits GEMMs in one launch: 32 x 396 grid, 3 blocks/CU
    gemm_sumexp_all<<<dim3(32, NBH + NBT1 + NBT + NBT), blk, 0, stream>>>(
        A8, WH8, WT18, WT28, WT38, bpH, bp1, bp2, bp3, pH, pT1, pT2, pT3);

    pals_finalize<<<dim3(NROW / 4), blk, 0, stream>>>(
        Hb, target, w0, b0, w1, b1, w2, b2, w3, b3, cw, cbv,
        pH, pT1, pT2, pT3, (float*)d_out);
}